// Round 1
// baseline (807.215 us; speedup 1.0000x reference)
//
#include <hip/hip_runtime.h>
#include <math.h>

typedef __attribute__((ext_vector_type(4))) float f32x4;
typedef __attribute__((ext_vector_type(2))) unsigned int u32x2;
typedef __attribute__((ext_vector_type(4))) unsigned int u32x4;
typedef __attribute__((ext_vector_type(8))) unsigned short u16x8;
typedef __attribute__((ext_vector_type(8))) __bf16 bf16x8;
typedef unsigned short ushort_t;

#define H_DIM 2048
#define T_TOK 2048
#define NEXP 16
#define I_DIM 1408
#define I2_DIM 2816
#define IS_DIM 5632
#define MAXROWS 6144
#define LDT 40  // LDS row stride (bf16 elems): 80B, 16B-aligned, bank-balanced

static __device__ __forceinline__ unsigned short f2bf(float f){
  union { float f; unsigned u; } v; v.f = f;
  unsigned r = v.u + 0x7FFFu + ((v.u >> 16) & 1u);
  return (unsigned short)(r >> 16);
}
static __device__ __forceinline__ float bf2f(unsigned short h){
  union { unsigned u; float f; } v; v.u = ((unsigned)h) << 16;
  return v.f;
}
static __device__ __forceinline__ float silu_f(float x){ return x / (1.f + __expf(-x)); }

// ---------------- cast x -> bf16 ----------------
__global__ void cast_bf16_k(const float* __restrict__ in, ushort_t* __restrict__ out){
  long i = ((long)blockIdx.x * 256 + threadIdx.x) * 8;
  f32x4 a = *(const f32x4*)&in[i];
  f32x4 b = *(const f32x4*)&in[i + 4];
  union { ushort_t s[8]; u32x4 v; } pk;
  #pragma unroll
  for (int j = 0; j < 4; j++){ pk.s[j] = f2bf(a[j]); pk.s[j+4] = f2bf(b[j]); }
  *(u32x4*)&out[i] = pk.v;
}

// ---------------- transpose + cast weights: in[z][K][N] fp32 -> out[z][N][K] bf16 ----------------
__global__ void transpose_cast_k(const float* __restrict__ in, ushort_t* __restrict__ out,
                                 int K, int N){
  long zo = (long)blockIdx.z * K * N;
  in += zo; out += zo;
  __shared__ float tl[32][33];
  int n0 = blockIdx.x * 32, k0 = blockIdx.y * 32;
  int tid = threadIdx.x;
  int tx = tid & 31, ty = tid >> 5;   // 32 x 8
  #pragma unroll
  for (int j = 0; j < 4; j++)
    tl[ty + j*8][tx] = in[(long)(k0 + ty + j*8) * N + n0 + tx];
  __syncthreads();
  int nl = tid >> 3, kc = (tid & 7) * 4;
  unsigned w0 = (unsigned)f2bf(tl[kc+0][nl]) | ((unsigned)f2bf(tl[kc+1][nl]) << 16);
  unsigned w1 = (unsigned)f2bf(tl[kc+2][nl]) | ((unsigned)f2bf(tl[kc+3][nl]) << 16);
  u32x2 o; o[0] = w0; o[1] = w1;
  *(u32x2*)&out[(long)(n0 + nl) * K + k0 + kc] = o;
}

// ---------------- router: logits, top-2 renorm, shared gate, compaction ----------------
__global__ void router_k(const float* __restrict__ x, const float* __restrict__ rw,
                         const float* __restrict__ sgw, float* __restrict__ logits,
                         int* __restrict__ counts, int* __restrict__ lists,
                         float* __restrict__ probs, float* __restrict__ sgmul){
  int wid = threadIdx.x >> 6, lane = threadIdx.x & 63;
  int t = blockIdx.x * 4 + wid;
  const float* xr = x + (long)t * H_DIM;
  float acc[17];
  #pragma unroll
  for (int e = 0; e < 17; e++) acc[e] = 0.f;
  for (int h0 = lane * 4; h0 < H_DIM; h0 += 256){
    f32x4 xv = *(const f32x4*)&xr[h0];
    #pragma unroll
    for (int i = 0; i < 4; i++){
      float xs = xv[i];
      const float* wrow = rw + (long)(h0 + i) * NEXP;
      #pragma unroll
      for (int e = 0; e < 16; e++) acc[e] += xs * wrow[e];
      acc[16] += xs * sgw[h0 + i];
    }
  }
  #pragma unroll
  for (int e = 0; e < 17; e++)
    for (int off = 32; off >= 1; off >>= 1)
      acc[e] += __shfl_xor(acc[e], off);
  if (lane == 0){
    float* lo = logits + (long)t * NEXP;
    #pragma unroll
    for (int e = 0; e < 16; e++) lo[e] = acc[e];
    int e0 = 0;
    #pragma unroll
    for (int e = 1; e < 16; e++) if (acc[e] > acc[e0]) e0 = e;
    int e1 = (e0 == 0) ? 1 : 0;
    #pragma unroll
    for (int e = 0; e < 16; e++) if (e != e0 && acc[e] > acc[e1]) e1 = e;
    float d = acc[e1] - acc[e0];       // <= 0
    float ed = __expf(d);
    float p0 = 1.f / (1.f + ed);
    float p1 = ed / (1.f + ed);
    int pos0 = atomicAdd(&counts[e0], 1);
    lists[e0 * T_TOK + pos0] = t; probs[e0 * T_TOK + pos0] = p0;
    int pos1 = atomicAdd(&counts[e1], 1);
    lists[e1 * T_TOK + pos1] = t; probs[e1 * T_TOK + pos1] = p1;
    sgmul[t] = 1.f / (1.f + __expf(-acc[16]));
  }
}

// ---------------- padded prefix bases ----------------
__global__ void bases_k(const int* __restrict__ counts, int* __restrict__ bases){
  if (threadIdx.x == 0){
    int r = 0;
    for (int e = 0; e < NEXP; e++){ bases[e] = r; r += (counts[e] + 127) & ~127; }
  }
}

// ---------------- SwiGLU elementwise ----------------
__global__ void swiglu_expert_k(const ushort_t* __restrict__ gu, ushort_t* __restrict__ hid){
  long q = (long)blockIdx.x * 256 + threadIdx.x;
  long r = q / (I_DIM / 8); int ic = (int)(q % (I_DIM / 8)) * 8;
  const ushort_t* g = gu + r * I2_DIM + ic;
  u16x8 gv = *(const u16x8*)g;
  u16x8 uv = *(const u16x8*)(g + I_DIM);
  u16x8 ov;
  #pragma unroll
  for (int i = 0; i < 8; i++)
    ov[i] = f2bf(bf2f(uv[i]) * silu_f(bf2f(gv[i])));
  *(u16x8*)&hid[r * I_DIM + ic] = ov;
}

__global__ void swiglu_flat_k(ushort_t* __restrict__ sg, const ushort_t* __restrict__ si){
  long i = ((long)blockIdx.x * 256 + threadIdx.x) * 8;
  u16x8 g = *(const u16x8*)&sg[i];
  u16x8 s = *(const u16x8*)&si[i];
  u16x8 o;
  #pragma unroll
  for (int j = 0; j < 8; j++)
    o[j] = f2bf(bf2f(s[j]) * silu_f(bf2f(g[j])));
  *(u16x8*)&sg[i] = o;
}

// ---------------- GEMM: A[M][K] bf16 (opt gathered), Bt[N][K] bf16 ----------------
// MODE 0: raw bf16 store to Cb.  MODE 1: expert gate_up, gather A rows via lists, masked store.
// MODE 2: expert out, atomicAdd p*val into outp scattered by token.  MODE 3: store svec[m]*val to outp.
template<int MODE>
__global__ void gemm_k(const ushort_t* __restrict__ A, const ushort_t* __restrict__ Bt,
                       ushort_t* __restrict__ Cb,
                       int M, int N, int K, int lda, int ldbt, int ldc,
                       const int* __restrict__ counts, const int* __restrict__ bases,
                       const int* __restrict__ lists, const float* __restrict__ probs,
                       const float* __restrict__ svec, float* __restrict__ outp,
                       long bstride){
  int z = blockIdx.z;
  int cnt = M;
  const ushort_t* Ab = A;
  const ushort_t* Bb = Bt;
  long rbase = 0;
  if constexpr (MODE == 1){ cnt = counts[z]; rbase = bases[z]; Bb += (long)z * bstride; }
  if constexpr (MODE == 2){ cnt = counts[z]; Ab += (long)bases[z] * lda; Bb += (long)z * bstride; }
  int m0 = blockIdx.y * 128;
  if (m0 >= cnt) return;
  int n0 = blockIdx.x * 128;

  __shared__ ushort_t As[128 * LDT];
  __shared__ ushort_t Bs[128 * LDT];

  int tid = threadIdx.x;
  int lane = tid & 63;
  int wr = (tid >> 7) & 1;
  int wc = (tid >> 6) & 1;

  int srow[2], skc[2];
  long aoff[2], boff[2];
  #pragma unroll
  for (int p = 0; p < 2; p++){
    int idx = p * 256 + tid;
    srow[p] = idx >> 2;
    skc[p]  = (idx & 3) * 8;
    int j = m0 + srow[p];
    if constexpr (MODE == 1){
      int jj = j < cnt ? j : cnt - 1;
      aoff[p] = (long)lists[z * T_TOK + jj] * lda + skc[p];
    } else {
      aoff[p] = (long)j * lda + skc[p];
    }
    boff[p] = (long)(n0 + srow[p]) * ldbt + skc[p];
  }

  u32x4 ar[2], br[2];
  #pragma unroll
  for (int p = 0; p < 2; p++){
    ar[p] = *(const u32x4*)(Ab + aoff[p]);
    br[p] = *(const u32x4*)(Bb + boff[p]);
  }

  f32x4 zero = {0.f, 0.f, 0.f, 0.f};
  f32x4 acc[4][4];
  #pragma unroll
  for (int i = 0; i < 4; i++)
    #pragma unroll
    for (int j = 0; j < 4; j++) acc[i][j] = zero;

  int nsteps = K / 32;
  for (int s = 0; s < nsteps; s++){
    __syncthreads();
    #pragma unroll
    for (int p = 0; p < 2; p++){
      *(u32x4*)&As[srow[p] * LDT + skc[p]] = ar[p];
      *(u32x4*)&Bs[srow[p] * LDT + skc[p]] = br[p];
    }
    __syncthreads();
    if (s + 1 < nsteps){
      int k0 = (s + 1) * 32;
      #pragma unroll
      for (int p = 0; p < 2; p++){
        ar[p] = *(const u32x4*)(Ab + aoff[p] + k0);
        br[p] = *(const u32x4*)(Bb + boff[p] + k0);
      }
    }
    bf16x8 af[4], bv[4];
    #pragma unroll
    for (int f = 0; f < 4; f++){
      af[f] = *(const bf16x8*)&As[(wr * 64 + f * 16 + (lane & 15)) * LDT + (lane >> 4) * 8];
      bv[f] = *(const bf16x8*)&Bs[(wc * 64 + f * 16 + (lane & 15)) * LDT + (lane >> 4) * 8];
    }
    #pragma unroll
    for (int fm = 0; fm < 4; fm++)
      #pragma unroll
      for (int fn = 0; fn < 4; fn++)
        acc[fm][fn] = __builtin_amdgcn_mfma_f32_16x16x32_bf16(af[fm], bv[fn], acc[fm][fn], 0, 0, 0);
  }

  int colb = n0 + wc * 64 + (lane & 15);
  int rowb = m0 + wr * 64 + (lane >> 4) * 4;
  #pragma unroll
  for (int fm = 0; fm < 4; fm++){
    #pragma unroll
    for (int fn = 0; fn < 4; fn++){
      f32x4 v = acc[fm][fn];
      int col = colb + fn * 16;
      #pragma unroll
      for (int r = 0; r < 4; r++){
        int m = rowb + fm * 16 + r;
        if constexpr (MODE == 0){
          Cb[(long)m * ldc + col] = f2bf(v[r]);
        } else if constexpr (MODE == 1){
          if (m < cnt) Cb[(rbase + m) * (long)ldc + col] = f2bf(v[r]);
        } else if constexpr (MODE == 2){
          if (m < cnt){
            int tok = lists[z * T_TOK + m];
            float p = probs[z * T_TOK + m];
            atomicAdd(outp + (long)tok * ldc + col, p * v[r]);
          }
        } else {
          outp[(long)m * ldc + col] = svec[m] * v[r];
        }
      }
    }
  }
}

extern "C" void kernel_launch(void* const* d_in, const int* in_sizes, int n_in,
                              void* d_out, int out_size, void* d_ws, size_t ws_size,
                              hipStream_t stream){
  const float* x    = (const float*)d_in[0];
  const float* rw   = (const float*)d_in[1];
  const float* wgu  = (const float*)d_in[2];
  const float* wout = (const float*)d_in[3];
  const float* wsg  = (const float*)d_in[4];
  const float* wsi  = (const float*)d_in[5];
  const float* wso  = (const float*)d_in[6];
  const float* sgw  = (const float*)d_in[7];

  float* out = (float*)d_out;
  float* logits = out + (size_t)T_TOK * H_DIM;

  char* w = (char*)d_ws;
  auto alloc = [&](size_t b){ char* p = w; w += (b + 255) & ~(size_t)255; return p; };
  ushort_t* xb     = (ushort_t*)alloc((size_t)T_TOK * H_DIM * 2);
  ushort_t* wgu_t  = (ushort_t*)alloc((size_t)NEXP * I2_DIM * H_DIM * 2);
  ushort_t* wout_t = (ushort_t*)alloc((size_t)NEXP * H_DIM * I_DIM * 2);
  ushort_t* wsg_t  = (ushort_t*)alloc((size_t)IS_DIM * H_DIM * 2);
  ushort_t* wsi_t  = (ushort_t*)alloc((size_t)IS_DIM * H_DIM * 2);
  ushort_t* wso_t  = (ushort_t*)alloc((size_t)H_DIM * IS_DIM * 2);
  ushort_t* sgr    = (ushort_t*)alloc((size_t)T_TOK * IS_DIM * 2);
  ushort_t* sir    = (ushort_t*)alloc((size_t)T_TOK * IS_DIM * 2);
  ushort_t* gu     = (ushort_t*)alloc((size_t)MAXROWS * I2_DIM * 2);
  ushort_t* hid    = (ushort_t*)alloc((size_t)MAXROWS * I_DIM * 2);
  int*   counts = (int*)alloc(64);
  int*   bases  = (int*)alloc(64);
  int*   lists  = (int*)alloc((size_t)NEXP * T_TOK * 4);
  float* probs  = (float*)alloc((size_t)NEXP * T_TOK * 4);
  float* sgmul  = (float*)alloc((size_t)T_TOK * 4);

  hipMemsetAsync(counts, 0, 64, stream);

  cast_bf16_k<<<2048, 256, 0, stream>>>(x, xb);
  transpose_cast_k<<<dim3(I2_DIM/32, H_DIM/32, NEXP), 256, 0, stream>>>(wgu, wgu_t, H_DIM, I2_DIM);
  transpose_cast_k<<<dim3(H_DIM/32, I_DIM/32, NEXP), 256, 0, stream>>>(wout, wout_t, I_DIM, H_DIM);
  transpose_cast_k<<<dim3(IS_DIM/32, H_DIM/32, 1), 256, 0, stream>>>(wsg, wsg_t, H_DIM, IS_DIM);
  transpose_cast_k<<<dim3(IS_DIM/32, H_DIM/32, 1), 256, 0, stream>>>(wsi, wsi_t, H_DIM, IS_DIM);
  transpose_cast_k<<<dim3(H_DIM/32, IS_DIM/32, 1), 256, 0, stream>>>(wso, wso_t, IS_DIM, H_DIM);

  router_k<<<512, 256, 0, stream>>>(x, rw, sgw, logits, counts, lists, probs, sgmul);
  bases_k<<<1, 64, 0, stream>>>(counts, bases);

  // shared expert path (writes out, initializing it)
  gemm_k<0><<<dim3(IS_DIM/128, T_TOK/128, 1), 256, 0, stream>>>(
      xb, wsg_t, sgr, T_TOK, IS_DIM, H_DIM, H_DIM, H_DIM, IS_DIM,
      nullptr, nullptr, nullptr, nullptr, nullptr, nullptr, 0);
  gemm_k<0><<<dim3(IS_DIM/128, T_TOK/128, 1), 256, 0, stream>>>(
      xb, wsi_t, sir, T_TOK, IS_DIM, H_DIM, H_DIM, H_DIM, IS_DIM,
      nullptr, nullptr, nullptr, nullptr, nullptr, nullptr, 0);
  swiglu_flat_k<<<(T_TOK * (IS_DIM/8)) / 256, 256, 0, stream>>>(sgr, sir);
  gemm_k<3><<<dim3(H_DIM/128, T_TOK/128, 1), 256, 0, stream>>>(
      sgr, wso_t, nullptr, T_TOK, H_DIM, IS_DIM, IS_DIM, IS_DIM, H_DIM,
      nullptr, nullptr, nullptr, nullptr, sgmul, out, 0);

  // sparse routed experts (atomic add on top of shared output)
  gemm_k<1><<<dim3(I2_DIM/128, T_TOK/128, NEXP), 256, 0, stream>>>(
      xb, wgu_t, gu, T_TOK, I2_DIM, H_DIM, H_DIM, H_DIM, I2_DIM,
      counts, bases, lists, probs, nullptr, nullptr, (long)I2_DIM * H_DIM);
  swiglu_expert_k<<<(MAXROWS * (I_DIM/8)) / 256, 256, 0, stream>>>(gu, hid);
  gemm_k<2><<<dim3(H_DIM/128, T_TOK/128, NEXP), 256, 0, stream>>>(
      hid, wout_t, nullptr, T_TOK, H_DIM, I_DIM, I_DIM, I_DIM, H_DIM,
      counts, bases, lists, probs, nullptr, out, (long)H_DIM * I_DIM);

  (void)in_sizes; (void)n_in; (void)out_size; (void)ws_size;
}